// Round 1
// baseline (553.068 us; speedup 1.0000x reference)
//
#include <hip/hip_runtime.h>

#define BATCH 32
#define DIM   128
#define NPTS  2048
#define BIGF  1e30f

// workspace layout (in float/int elements)
#define OFF_LENS 0                    // 32 ints (padded to 256)
#define OFF_XN   256
#define OFF_YN   (256 + BATCH*NPTS)
#define OFF_RMIN (256 + 2*BATCH*NPTS)
#define OFF_CMIN (256 + 3*BATCH*NPTS)

#define TI 128
#define TJ 128
#define DC 64

// ---------------- kernel 1: norms + lens + init ----------------
__global__ void chamfer_prep(const float* __restrict__ x,
                             const float* __restrict__ y,
                             const void* __restrict__ mask,
                             float* __restrict__ ws,
                             float* __restrict__ out) {
  __shared__ int red[256];
  int blk = blockIdx.x;        // BATCH*8 blocks
  int b = blk >> 3;
  int s = blk & 7;
  int tid = threadIdx.x;       // 256 threads
  int i = s * 256 + tid;       // one point per thread

  const float* xb = x + (size_t)b * DIM * NPTS + i;
  const float* yb = y + (size_t)b * DIM * NPTS + i;
  float sx = 0.f, sy = 0.f;
#pragma unroll 4
  for (int d = 0; d < DIM; ++d) {
    float xv = xb[(size_t)d * NPTS];
    float yv = yb[(size_t)d * NPTS];
    sx = fmaf(xv, xv, sx);
    sy = fmaf(yv, yv, sy);
  }
  ws[OFF_XN + b * NPTS + i] = sx;
  ws[OFF_YN + b * NPTS + i] = sy;
  ws[OFF_RMIN + b * NPTS + i] = BIGF;
  ws[OFF_CMIN + b * NPTS + i] = BIGF;

  if (s == 0) {
    // mask dtype detection: numpy bool (1B) vs int32 (4B).
    // mask[0][1] is guaranteed true (lens >= N/2), so byte 1 == 0 => int32.
    const unsigned char* mb = (const unsigned char*)mask;
    bool is_i32 = (mb[1] == 0);
    const int* mi = (const int*)mask;
    int cnt = 0;
    for (int n = tid; n < NPTS; n += 256) {
      bool v = is_i32 ? (mi[b * NPTS + n] != 0) : (mb[b * NPTS + n] != 0);
      cnt += v ? 1 : 0;
    }
    red[tid] = cnt;
    __syncthreads();
    for (int st = 128; st > 0; st >>= 1) {
      if (tid < st) red[tid] += red[tid + st];
      __syncthreads();
    }
    if (tid == 0) {
      ((int*)ws)[OFF_LENS + b] = red[0];
      if (b == 0) out[0] = 0.f;
    }
  }
}

// ---------------- kernel 2: tiled distance + mins ----------------
__launch_bounds__(256, 2)
__global__ void chamfer_dist(const float* __restrict__ x,
                             const float* __restrict__ y,
                             float* __restrict__ ws) {
  __shared__ float xs[DC][TI];     // 32 KB
  __shared__ float ys[DC][TJ];     // 32 KB
  __shared__ float cbuf[16][TJ];   // 8 KB

  const int ntile = NPTS / TI;     // 16
  int b = blockIdx.x / ntile;
  int it = blockIdx.x % ntile;
  int i0 = it * TI;
  int tid = threadIdx.x;
  int tx = tid & 15;
  int ty = tid >> 4;
  int len = ((const int*)ws)[OFF_LENS + b];

  const float* xb = x + (size_t)b * DIM * NPTS;
  const float* yb = y + (size_t)b * DIM * NPTS;
  const float* xn = ws + OFF_XN + b * NPTS;
  const float* yn = ws + OFF_YN + b * NPTS;
  float* rowmin = ws + OFF_RMIN + b * NPTS;
  unsigned int* colmin = (unsigned int*)(ws + OFF_CMIN) + b * NPTS;

  int im[8];
#pragma unroll
  for (int k = 0; k < 4; ++k) { im[k] = ty * 4 + k; im[4 + k] = 64 + ty * 4 + k; }

  float xnr[8];
#pragma unroll
  for (int m = 0; m < 8; ++m) xnr[m] = xn[i0 + im[m]];

  float rmin[8];
#pragma unroll
  for (int m = 0; m < 8; ++m) rmin[m] = BIGF;

  for (int j0 = 0; j0 < NPTS; j0 += TJ) {
    float acc[8][8];
#pragma unroll
    for (int m = 0; m < 8; ++m)
#pragma unroll
      for (int n = 0; n < 8; ++n) acc[m][n] = 0.f;

    for (int dc = 0; dc < DIM; dc += DC) {
      __syncthreads();   // previous consumers of xs/ys (and cbuf reduce) done
      // cooperative load: 64 rows x 128 cols for both xs and ys, float4
#pragma unroll
      for (int k = 0; k < 8; ++k) {
        int idx = tid + k * 256;   // 0..2047
        int r = idx >> 5;          // row 0..63
        int c4 = idx & 31;         // float4 col 0..31
        float4 v = *(const float4*)(xb + (size_t)(dc + r) * NPTS + i0 + c4 * 4);
        *(float4*)&xs[r][c4 * 4] = v;
        float4 w = *(const float4*)(yb + (size_t)(dc + r) * NPTS + j0 + c4 * 4);
        *(float4*)&ys[r][c4 * 4] = w;
      }
      __syncthreads();
#pragma unroll 2
      for (int d = 0; d < DC; ++d) {
        float4 a0 = *(const float4*)&xs[d][ty * 4];
        float4 a1 = *(const float4*)&xs[d][64 + ty * 4];
        float4 b0 = *(const float4*)&ys[d][tx * 4];
        float4 b1 = *(const float4*)&ys[d][64 + tx * 4];
        float av[8] = {a0.x, a0.y, a0.z, a0.w, a1.x, a1.y, a1.z, a1.w};
        float bv[8] = {b0.x, b0.y, b0.z, b0.w, b1.x, b1.y, b1.z, b1.w};
#pragma unroll
        for (int m = 0; m < 8; ++m)
#pragma unroll
          for (int n = 0; n < 8; ++n)
            acc[m][n] = fmaf(av[m], bv[n], acc[m][n]);
      }
    }

    // epilogue: distances + min updates
    int jm[8];
#pragma unroll
    for (int k = 0; k < 4; ++k) { jm[k] = tx * 4 + k; jm[4 + k] = 64 + tx * 4 + k; }
    float ynr[8], cm[8];
#pragma unroll
    for (int n = 0; n < 8; ++n) { ynr[n] = yn[j0 + jm[n]]; cm[n] = BIGF; }

#pragma unroll
    for (int m = 0; m < 8; ++m) {
      bool iv = (i0 + im[m]) < len;
#pragma unroll
      for (int n = 0; n < 8; ++n) {
        float dd = fmaxf(xnr[m] + ynr[n] - 2.f * acc[m][n], 0.f);
        bool jv = (j0 + jm[n]) < len;
        rmin[m] = fminf(rmin[m], jv ? dd : BIGF);
        cm[n] = fminf(cm[n], iv ? dd : BIGF);
      }
    }

    // column-min: reduce across ty via LDS, then atomicMin (nonneg float as uint)
    *(float4*)&cbuf[ty][tx * 4]      = make_float4(cm[0], cm[1], cm[2], cm[3]);
    *(float4*)&cbuf[ty][64 + tx * 4] = make_float4(cm[4], cm[5], cm[6], cm[7]);
    __syncthreads();
    if (tid < TJ) {
      float v = BIGF;
#pragma unroll
      for (int r = 0; r < 16; ++r) v = fminf(v, cbuf[r][tid]);
      atomicMin(&colmin[j0 + tid], __float_as_uint(v));
    }
    // next iteration's first __syncthreads protects cbuf/xs/ys overwrite
  }

  // row-min: reduce across tx (same-wave lanes), write direct (block owns rows)
#pragma unroll
  for (int m = 0; m < 8; ++m) {
    float v = rmin[m];
    v = fminf(v, __shfl_xor(v, 1));
    v = fminf(v, __shfl_xor(v, 2));
    v = fminf(v, __shfl_xor(v, 4));
    v = fminf(v, __shfl_xor(v, 8));
    if (tx == 0) rowmin[i0 + im[m]] = v;
  }
}

// ---------------- kernel 3: masked sums + mean ----------------
__global__ void chamfer_reduce(const float* __restrict__ ws, float* __restrict__ out) {
  __shared__ float red[256];
  int b = blockIdx.x;
  int tid = threadIdx.x;
  int len = ((const int*)ws)[OFF_LENS + b];
  const float* rowmin = ws + OFF_RMIN + b * NPTS;
  const float* colmin = ws + OFF_CMIN + b * NPTS;
  float s = 0.f;
  for (int i = tid; i < len; i += 256) s += rowmin[i] + colmin[i];
  red[tid] = s;
  __syncthreads();
  for (int st = 128; st > 0; st >>= 1) {
    if (tid < st) red[tid] += red[tid + st];
    __syncthreads();
  }
  if (tid == 0) atomicAdd(out, red[0] * (1.f / BATCH));
}

extern "C" void kernel_launch(void* const* d_in, const int* in_sizes, int n_in,
                              void* d_out, int out_size, void* d_ws, size_t ws_size,
                              hipStream_t stream) {
  const float* x = (const float*)d_in[0];
  const float* y = (const float*)d_in[1];
  const void* mask = d_in[2];
  float* out = (float*)d_out;
  float* ws = (float*)d_ws;

  chamfer_prep<<<BATCH * 8, 256, 0, stream>>>(x, y, mask, ws, out);
  chamfer_dist<<<BATCH * (NPTS / TI), 256, 0, stream>>>(x, y, ws);
  chamfer_reduce<<<BATCH, 256, 0, stream>>>(ws, out);
}

// Round 2
// 162.356 us; speedup vs baseline: 3.4065x; 3.4065x over previous
//
#include <hip/hip_runtime.h>
#include <hip/hip_bf16.h>

#define BATCH 32
#define DIM   128
#define NPTS  2048
#define BIGF  1e30f

// byte offsets in ws (total ~33 MB)
#define OFF_XT   0ull
#define OFF_YT   16777216ull
#define OFF_XN   33554432ull
#define OFF_YN   (33554432ull + 262144ull)
#define OFF_RMIN (33554432ull + 2ull * 262144ull)
#define OFF_CMIN (33554432ull + 3ull * 262144ull)

typedef __bf16 bf16x8 __attribute__((ext_vector_type(8)));
typedef float  f32x16 __attribute__((ext_vector_type(16)));

#define ZERO16 {0.f,0.f,0.f,0.f,0.f,0.f,0.f,0.f,0.f,0.f,0.f,0.f,0.f,0.f,0.f,0.f}

__device__ __forceinline__ bool mask_is_i32(const void* m) {
  // mask[0][1] is guaranteed true (lens >= N/2 > 1); for int32 its byte 1 is 0.
  return ((const unsigned char*)m)[1] == 0;
}
__device__ __forceinline__ bool mask_at(const void* m, bool i32, int idx) {
  return i32 ? (((const int*)m)[idx] != 0) : (((const unsigned char*)m)[idx] != 0);
}

// ---------------- kernel 1: transpose to bf16 + norms (mask-folded) + init ----------------
__global__ void chamfer_prep(const float* __restrict__ x, const float* __restrict__ y,
                             const void* __restrict__ mask, char* __restrict__ ws,
                             float* __restrict__ out) {
  int blk = blockIdx.x;
  int arr = blk >> 12;          // 0 = x, 1 = y
  int b   = (blk >> 7) & 31;
  int pt  = blk & 127;
  int n0  = pt << 4;            // 16 points per block
  int tid = threadIdx.x;
  int p = tid & 15, c = tid >> 4;   // p: point, c: chunk of 8 dims

  const float* src = (arr ? y : x) + (size_t)b * DIM * NPTS;
  unsigned short* dstT = (unsigned short*)(ws + (arr ? OFF_YT : OFF_XT))
                         + ((size_t)b * NPTS + n0 + p) * DIM + c * 8;
  float sq = 0.f;
  unsigned short h[8];
#pragma unroll
  for (int q = 0; q < 8; ++q) {
    float v = src[(size_t)(c * 8 + q) * NPTS + n0 + p];   // coalesced 64B segments
    __hip_bfloat16 bv = __float2bfloat16(v);
    h[q] = *(unsigned short*)&bv;
    float vb = __bfloat162float(bv);
    sq = fmaf(vb, vb, sq);      // norm from the ROUNDED value (consistent with MFMA)
  }
  uint4 pk;
  pk.x = h[0] | ((unsigned)h[1] << 16);
  pk.y = h[2] | ((unsigned)h[3] << 16);
  pk.z = h[4] | ((unsigned)h[5] << 16);
  pk.w = h[6] | ((unsigned)h[7] << 16);
  *(uint4*)dstT = pk;

  __shared__ float s[256];
  s[tid] = sq;
  __syncthreads();
  if (tid < 16) {
    float tot = 0.f;
#pragma unroll
    for (int cc = 0; cc < 16; ++cc) tot += s[cc * 16 + tid];
    int j = n0 + tid;
    bool i32 = mask_is_i32(mask);
    bool valid = mask_at(mask, i32, b * NPTS + j);
    float nr = valid ? tot : BIGF;   // mask folded into norm
    float* nrm = (float*)(ws + (arr ? OFF_YN : OFF_XN));
    nrm[b * NPTS + j] = nr;
    if (arr) ((unsigned*)(ws + OFF_CMIN))[b * NPTS + j] = __float_as_uint(BIGF);
  }
  if (blk == 0 && tid == 0) out[0] = 0.f;
}

// ---------------- kernel 2: MFMA distance + mins ----------------
__global__ __launch_bounds__(512, 2)
void chamfer_dist(char* __restrict__ ws) {
  __shared__ unsigned short xs[256 * 128];     // 64 KB, swizzled
  __shared__ unsigned short ys[2][128 * 128];  // 2 x 32 KB, double-buffered
  __shared__ unsigned colmin_lds[NPTS];        // 8 KB

  int blk = blockIdx.x;
  int b  = blk & 31;            // batch fast -> same batch's 8 i-tiles share an XCD L2
  int it = blk >> 5;
  int i0 = it << 8;             // i-tile of 256
  int tid  = threadIdx.x;
  int lane = tid & 63;
  int w    = tid >> 6;          // 8 waves: 4 row-quadrants x 2 col-halves
  int qrow = w >> 1, qcol = w & 1;
  int la31 = lane & 31, la5 = lane >> 5;

  const char* xTb = ws + OFF_XT + (size_t)b * NPTS * DIM * 2;
  const char* yTb = ws + OFF_YT + (size_t)b * NPTS * DIM * 2;
  const float* xng = (const float*)(ws + OFF_XN) + b * NPTS;
  const float* yng = (const float*)(ws + OFF_YN) + b * NPTS;
  float*    rowming = (float*)(ws + OFF_RMIN) + b * NPTS;
  unsigned* colming = (unsigned*)(ws + OFF_CMIN) + b * NPTS;

#pragma unroll
  for (int k = 0; k < NPTS / 512; ++k)
    colmin_lds[k * 512 + tid] = __float_as_uint(BIGF);

  char* xsb = (char*)xs;
  // stage xs: 256 pts x 128 d bf16, swizzle byte ^= (pt&7)<<4
#pragma unroll
  for (int k = 0; k < 8; ++k) {
    int idx = k * 512 + tid;
    int p = idx >> 4, cc = idx & 15;
    uint4 v = *(const uint4*)(xTb + (size_t)(i0 + p) * 256 + cc * 16);
    *(uint4*)(xsb + p * 256 + ((cc * 16) ^ ((p & 7) << 4))) = v;
  }
  // stage ys[0]
  {
    char* dst = (char*)ys[0];
#pragma unroll
    for (int k = 0; k < 4; ++k) {
      int idx = k * 512 + tid;
      int p = idx >> 4, cc = idx & 15;
      uint4 v = *(const uint4*)(yTb + (size_t)p * 256 + cc * 16);
      *(uint4*)(dst + p * 256 + ((cc * 16) ^ ((p & 7) << 4))) = v;
    }
  }

  // preload xn for this wave's 64 rows (C/D layout: row=(r&3)+8*(r>>2)+4*la5, col=la31)
  float xnr[2][16];
#pragma unroll
  for (int fm = 0; fm < 2; ++fm)
#pragma unroll
    for (int r = 0; r < 16; ++r) {
      int row = qrow * 64 + fm * 32 + (r & 3) + ((r >> 2) << 3) + (la5 << 2);
      xnr[fm][r] = xng[i0 + row];
    }
  float rmin[2][16];
#pragma unroll
  for (int fm = 0; fm < 2; ++fm)
#pragma unroll
    for (int r = 0; r < 16; ++r) rmin[fm][r] = BIGF;

  __syncthreads();

  int sx = (la31 & 7) << 4;                    // read-side swizzle (matches write side)
  int prow0 = (qrow * 64 + la31) * 256;
  int prow1 = prow0 + 32 * 256;
  int pcol0 = (qcol * 64 + la31) * 256;
  int pcol1 = pcol0 + 32 * 256;

  for (int jt = 0; jt < 16; ++jt) {
    int cur = jt & 1;
    // T14 async split: issue next tile's global loads before compute
    uint4 stg0, stg1, stg2, stg3;
    if (jt < 15) {
      const char* base = yTb + (size_t)(jt + 1) * 128 * 256;
      int i0d = tid, i1d = 512 + tid, i2d = 1024 + tid, i3d = 1536 + tid;
      stg0 = *(const uint4*)(base + (i0d >> 4) * 256 + (i0d & 15) * 16);
      stg1 = *(const uint4*)(base + (i1d >> 4) * 256 + (i1d & 15) * 16);
      stg2 = *(const uint4*)(base + (i2d >> 4) * 256 + (i2d & 15) * 16);
      stg3 = *(const uint4*)(base + (i3d >> 4) * 256 + (i3d & 15) * 16);
    }
    int j0t = jt * 128 + qcol * 64;
    float ynr0 = yng[j0t + la31];
    float ynr1 = yng[j0t + 32 + la31];

    const char* ysb = (const char*)ys[cur];
    f32x16 acc00 = ZERO16, acc01 = ZERO16, acc10 = ZERO16, acc11 = ZERO16;
#pragma unroll
    for (int kc = 0; kc < 8; ++kc) {
      int dbs = (kc * 32 + la5 * 16) ^ sx;
      bf16x8 a0 = *(const bf16x8*)(xsb + prow0 + dbs);
      bf16x8 a1 = *(const bf16x8*)(xsb + prow1 + dbs);
      bf16x8 b0 = *(const bf16x8*)(ysb + pcol0 + dbs);
      bf16x8 b1 = *(const bf16x8*)(ysb + pcol1 + dbs);
      acc00 = __builtin_amdgcn_mfma_f32_32x32x16_bf16(a0, b0, acc00, 0, 0, 0);
      acc01 = __builtin_amdgcn_mfma_f32_32x32x16_bf16(a0, b1, acc01, 0, 0, 0);
      acc10 = __builtin_amdgcn_mfma_f32_32x32x16_bf16(a1, b0, acc10, 0, 0, 0);
      acc11 = __builtin_amdgcn_mfma_f32_32x32x16_bf16(a1, b1, acc11, 0, 0, 0);
    }
    // epilogue: d = xn + yn - 2*dot (invalid points carry BIG norms -> auto-masked)
    float cm0 = BIGF, cm1 = BIGF;
#pragma unroll
    for (int r = 0; r < 16; ++r) {
      float d;
      d = fmaxf(fmaf(-2.f, acc00[r], xnr[0][r] + ynr0), 0.f);
      rmin[0][r] = fminf(rmin[0][r], d); cm0 = fminf(cm0, d);
      d = fmaxf(fmaf(-2.f, acc01[r], xnr[0][r] + ynr1), 0.f);
      rmin[0][r] = fminf(rmin[0][r], d); cm1 = fminf(cm1, d);
      d = fmaxf(fmaf(-2.f, acc10[r], xnr[1][r] + ynr0), 0.f);
      rmin[1][r] = fminf(rmin[1][r], d); cm0 = fminf(cm0, d);
      d = fmaxf(fmaf(-2.f, acc11[r], xnr[1][r] + ynr1), 0.f);
      rmin[1][r] = fminf(rmin[1][r], d); cm1 = fminf(cm1, d);
    }
    cm0 = fminf(cm0, __shfl_xor(cm0, 32));
    cm1 = fminf(cm1, __shfl_xor(cm1, 32));
    if (lane < 32) {
      atomicMin(&colmin_lds[jt * 128 + qcol * 64 + la31],      __float_as_uint(cm0));
      atomicMin(&colmin_lds[jt * 128 + qcol * 64 + 32 + la31], __float_as_uint(cm1));
    }
    // land the prefetched tile into the other buffer
    if (jt < 15) {
      char* dst = (char*)ys[cur ^ 1];
      int i0d = tid, i1d = 512 + tid, i2d = 1024 + tid, i3d = 1536 + tid;
      *(uint4*)(dst + (i0d >> 4) * 256 + (((i0d & 15) * 16) ^ (((i0d >> 4) & 7) << 4))) = stg0;
      *(uint4*)(dst + (i1d >> 4) * 256 + (((i1d & 15) * 16) ^ (((i1d >> 4) & 7) << 4))) = stg1;
      *(uint4*)(dst + (i2d >> 4) * 256 + (((i2d & 15) * 16) ^ (((i2d >> 4) & 7) << 4))) = stg2;
      *(uint4*)(dst + (i3d >> 4) * 256 + (((i3d & 15) * 16) ^ (((i3d >> 4) & 7) << 4))) = stg3;
    }
    __syncthreads();
  }

  // colmin: all LDS atomics complete as of the loop's final barrier
  for (int idx = tid; idx < NPTS; idx += 512)
    atomicMin(&colming[idx], colmin_lds[idx]);

  // rowmin: reduce across the 32 j-lanes, write direct (rows owned by this block)
#pragma unroll
  for (int fm = 0; fm < 2; ++fm)
#pragma unroll
    for (int r = 0; r < 16; ++r) {
      float v = rmin[fm][r];
      v = fminf(v, __shfl_xor(v, 1));
      v = fminf(v, __shfl_xor(v, 2));
      v = fminf(v, __shfl_xor(v, 4));
      v = fminf(v, __shfl_xor(v, 8));
      v = fminf(v, __shfl_xor(v, 16));
      if (la31 == 0) {
        int row = qrow * 64 + fm * 32 + (r & 3) + ((r >> 2) << 3) + (la5 << 2);
        rowming[i0 + row] = v;
      }
    }
}

// ---------------- kernel 3: masked sums + mean ----------------
__global__ void chamfer_reduce(const char* __restrict__ ws, const void* __restrict__ mask,
                               float* __restrict__ out) {
  __shared__ float red[256];
  int b = blockIdx.x;
  int tid = threadIdx.x;
  bool i32 = mask_is_i32(mask);
  const float*    rowmin = (const float*)(ws + OFF_RMIN) + b * NPTS;
  const unsigned* colmin = (const unsigned*)(ws + OFF_CMIN) + b * NPTS;
  float s = 0.f;
  for (int i = tid; i < NPTS; i += 256) {
    if (mask_at(mask, i32, b * NPTS + i))
      s += rowmin[i] + __uint_as_float(colmin[i]);
  }
  red[tid] = s;
  __syncthreads();
  for (int st = 128; st > 0; st >>= 1) {
    if (tid < st) red[tid] += red[tid + st];
    __syncthreads();
  }
  if (tid == 0) atomicAdd(out, red[0] * (1.f / BATCH));
}

extern "C" void kernel_launch(void* const* d_in, const int* in_sizes, int n_in,
                              void* d_out, int out_size, void* d_ws, size_t ws_size,
                              hipStream_t stream) {
  const float* x = (const float*)d_in[0];
  const float* y = (const float*)d_in[1];
  const void* mask = d_in[2];
  float* out = (float*)d_out;
  char* ws = (char*)d_ws;

  chamfer_prep<<<8192, 256, 0, stream>>>(x, y, mask, ws, out);
  chamfer_dist<<<256, 512, 0, stream>>>(ws);
  chamfer_reduce<<<32, 256, 0, stream>>>(ws, mask, out);
}

// Round 3
// 159.185 us; speedup vs baseline: 3.4744x; 1.0199x over previous
//
#include <hip/hip_runtime.h>
#include <hip/hip_bf16.h>

#define BATCH 32
#define DIM   128
#define NPTS  2048
#define BIGF  1e30f

// byte offsets in ws (total ~34 MB)
// xT/yT are stored as a pre-swizzled bf16 image: row r (point index), 16 chunks
// of 16B; data chunk c lives at image position c ^ (r & 7).
#define OFF_XT   0ull
#define OFF_YT   16777216ull
#define OFF_XN   33554432ull
#define OFF_YN   (33554432ull + 262144ull)
#define OFF_RMIN (33554432ull + 2ull * 262144ull)
#define OFF_CMIN (33554432ull + 3ull * 262144ull)

typedef __bf16 bf16x8 __attribute__((ext_vector_type(8)));
typedef float  f32x16 __attribute__((ext_vector_type(16)));

#define ZERO16 {0.f,0.f,0.f,0.f,0.f,0.f,0.f,0.f,0.f,0.f,0.f,0.f,0.f,0.f,0.f,0.f}

__device__ __forceinline__ bool mask_is_i32(const void* m) {
  // mask[0][1] is guaranteed true (lens >= N/2 > 1); for int32 its byte 1 is 0.
  return ((const unsigned char*)m)[1] == 0;
}
__device__ __forceinline__ bool mask_at(const void* m, bool i32, int idx) {
  return i32 ? (((const int*)m)[idx] != 0) : (((const unsigned char*)m)[idx] != 0);
}

// -------- kernel 1: coalesced transpose to bf16 image + norms + init --------
// grid: 2 arr x 32 b x 16 ntile = 1024 blocks, 256 threads
// tile: 128 d x 128 n, staged as f32 in LDS (pitch 132 floats)
__global__ void chamfer_prep(const float* __restrict__ x, const float* __restrict__ y,
                             const void* __restrict__ mask, char* __restrict__ ws,
                             float* __restrict__ out) {
  __shared__ float buf[128 * 132];      // [d][n], pitch 132 (528B, 16B-aligned)
  __shared__ float nrm_part[2][128];

  int blk = blockIdx.x;
  int arr = blk >> 9;
  int b   = (blk >> 4) & 31;
  int nt  = blk & 15;
  int n0  = nt << 7;                    // 128 points per block
  int tid = threadIdx.x;

  const float* src = (arr ? y : x) + (size_t)b * DIM * NPTS;

  // phase 1: fully-coalesced row reads (32 float4-lanes = 512B per d-row)
#pragma unroll
  for (int k = 0; k < 16; ++k) {
    int idx = k * 256 + tid;            // 0..4095 = 128 d x 32 c4
    int d = idx >> 5, c4 = idx & 31;
    float4 v = *(const float4*)(src + (size_t)d * NPTS + n0 + c4 * 4);
    *(float4*)&buf[d * 132 + c4 * 4] = v;
  }
  __syncthreads();

  // phase 2: column pass -> bf16 pack + norm; banks (4d+n)%32 -> 2-way (free)
  int n = tid & 127, half = tid >> 7;   // half: d in [half*64, half*64+64)
  char* img = ws + (arr ? OFF_YT : OFF_XT) + ((size_t)b * NPTS + n0 + n) * 256;
  float sq = 0.f;
#pragma unroll
  for (int cl = 0; cl < 8; ++cl) {
    unsigned short h[8];
#pragma unroll
    for (int q = 0; q < 8; ++q) {
      int d = half * 64 + cl * 8 + q;
      float v = buf[d * 132 + n];
      __hip_bfloat16 bv = __float2bfloat16(v);
      h[q] = *(unsigned short*)&bv;
      float vb = __bfloat162float(bv);
      sq = fmaf(vb, vb, sq);            // norm from ROUNDED value (matches MFMA)
    }
    uint4 pk;
    pk.x = h[0] | ((unsigned)h[1] << 16);
    pk.y = h[2] | ((unsigned)h[3] << 16);
    pk.z = h[4] | ((unsigned)h[5] << 16);
    pk.w = h[6] | ((unsigned)h[7] << 16);
    int cg = half * 8 + cl;             // data chunk index 0..15
    *(uint4*)(img + ((cg ^ (n & 7)) << 4)) = pk;   // pre-swizzled image
  }
  nrm_part[half][n] = sq;
  __syncthreads();
  if (half == 0) {
    float tot = nrm_part[0][n] + nrm_part[1][n];
    int row = n0 + n;
    bool i32 = mask_is_i32(mask);
    bool valid = mask_at(mask, i32, b * NPTS + row);
    float* nrm = (float*)(ws + (arr ? OFF_YN : OFF_XN));
    nrm[b * NPTS + row] = valid ? tot : BIGF;     // mask folded into norm
    if (arr) ((unsigned*)(ws + OFF_CMIN))[b * NPTS + row] = __float_as_uint(BIGF);
  }
  if (blk == 0 && tid == 0) out[0] = 0.f;
}

// -------- kernel 2: MFMA distance + mins (A-fragments in registers) --------
__global__ __launch_bounds__(512, 2)
void chamfer_dist(char* __restrict__ ws) {
  __shared__ unsigned short ys[2][128 * 128];  // 2 x 32 KB, double-buffered
  __shared__ unsigned colmin_lds[NPTS];        // 8 KB

  int blk = blockIdx.x;
  int b  = blk & 31;            // batch-fast: a batch's 8 i-tiles share an XCD L2
  int it = blk >> 5;
  int i0 = it << 8;             // i-tile of 256
  int tid  = threadIdx.x;
  int lane = tid & 63;
  int w    = tid >> 6;          // 8 waves: 4 row-quadrants x 2 col-halves
  int qrow = w >> 1, qcol = w & 1;
  int la31 = lane & 31, la5 = lane >> 5;

  const char* xTb = ws + OFF_XT + (size_t)b * NPTS * 256;
  const char* yTb = ws + OFF_YT + (size_t)b * NPTS * 256;
  const float* xng = (const float*)(ws + OFF_XN) + b * NPTS;
  const float* yng = (const float*)(ws + OFF_YN) + b * NPTS;
  float*    rowming = (float*)(ws + OFF_RMIN) + b * NPTS;
  unsigned* colming = (unsigned*)(ws + OFF_CMIN) + b * NPTS;

#pragma unroll
  for (int k = 0; k < NPTS / 512; ++k)
    colmin_lds[k * 512 + tid] = __float_as_uint(BIGF);

  // A fragments -> registers once (one-time strided L2 reads, reused 16 jt)
  int r0 = i0 + qrow * 64 + la31;           // r1 = r0+32 has same (r&7)
  int swA = (la31 & 7) << 4;
  const char* xrow0 = xTb + (size_t)r0 * 256;
  const char* xrow1 = xrow0 + 32 * 256;
  bf16x8 Areg0[8], Areg1[8];
#pragma unroll
  for (int kc = 0; kc < 8; ++kc) {
    int dbs = (((kc * 2 + la5) << 4)) ^ swA;
    Areg0[kc] = *(const bf16x8*)(xrow0 + dbs);
    Areg1[kc] = *(const bf16x8*)(xrow1 + dbs);
  }

  // preload xn for this wave's rows (C/D layout: row=(r&3)+8*(r>>2)+4*la5)
  float xnr[2][16];
#pragma unroll
  for (int fm = 0; fm < 2; ++fm)
#pragma unroll
    for (int r = 0; r < 16; ++r) {
      int row = qrow * 64 + fm * 32 + (r & 3) + ((r >> 2) << 3) + (la5 << 2);
      xnr[fm][r] = xng[i0 + row];
    }
  float rmin[2][16];
#pragma unroll
  for (int fm = 0; fm < 2; ++fm)
#pragma unroll
    for (int r = 0; r < 16; ++r) rmin[fm][r] = BIGF;

  // stage ys[0]: image is pre-swizzled -> pure linear copy (conflict-free)
#pragma unroll
  for (int k = 0; k < 4; ++k) {
    int idx = k * 512 + tid;
    *(uint4*)((char*)ys[0] + idx * 16) = *(const uint4*)(yTb + (size_t)idx * 16);
  }
  __syncthreads();

  int sw = (la31 & 7) << 4;
  int pcol0 = (qcol * 64 + la31) * 256;
  int pcol1 = pcol0 + 32 * 256;

  for (int jt = 0; jt < 16; ++jt) {
    int cur = jt & 1;
    // T14 async split: issue next tile's global loads before compute
    uint4 stg0, stg1, stg2, stg3;
    if (jt < 15) {
      const char* base = yTb + (size_t)(jt + 1) * 128 * 256;
      stg0 = *(const uint4*)(base + (size_t)(tid)        * 16);
      stg1 = *(const uint4*)(base + (size_t)(512  + tid) * 16);
      stg2 = *(const uint4*)(base + (size_t)(1024 + tid) * 16);
      stg3 = *(const uint4*)(base + (size_t)(1536 + tid) * 16);
    }
    int j0t = jt * 128 + qcol * 64;
    float ynr0 = yng[j0t + la31];
    float ynr1 = yng[j0t + 32 + la31];

    const char* ysb = (const char*)ys[cur];
    f32x16 acc00 = ZERO16, acc01 = ZERO16, acc10 = ZERO16, acc11 = ZERO16;
#pragma unroll
    for (int kc = 0; kc < 8; ++kc) {
      int dbs = ((kc * 2 + la5) << 4) ^ sw;
      bf16x8 b0 = *(const bf16x8*)(ysb + pcol0 + dbs);
      bf16x8 b1 = *(const bf16x8*)(ysb + pcol1 + dbs);
      acc00 = __builtin_amdgcn_mfma_f32_32x32x16_bf16(Areg0[kc], b0, acc00, 0, 0, 0);
      acc01 = __builtin_amdgcn_mfma_f32_32x32x16_bf16(Areg0[kc], b1, acc01, 0, 0, 0);
      acc10 = __builtin_amdgcn_mfma_f32_32x32x16_bf16(Areg1[kc], b0, acc10, 0, 0, 0);
      acc11 = __builtin_amdgcn_mfma_f32_32x32x16_bf16(Areg1[kc], b1, acc11, 0, 0, 0);
    }
    // epilogue: d = xn + yn - 2*dot (invalid points carry BIG norms)
    float cm0 = BIGF, cm1 = BIGF;
#pragma unroll
    for (int r = 0; r < 16; ++r) {
      float d;
      d = fmaxf(fmaf(-2.f, acc00[r], xnr[0][r] + ynr0), 0.f);
      rmin[0][r] = fminf(rmin[0][r], d); cm0 = fminf(cm0, d);
      d = fmaxf(fmaf(-2.f, acc01[r], xnr[0][r] + ynr1), 0.f);
      rmin[0][r] = fminf(rmin[0][r], d); cm1 = fminf(cm1, d);
      d = fmaxf(fmaf(-2.f, acc10[r], xnr[1][r] + ynr0), 0.f);
      rmin[1][r] = fminf(rmin[1][r], d); cm0 = fminf(cm0, d);
      d = fmaxf(fmaf(-2.f, acc11[r], xnr[1][r] + ynr1), 0.f);
      rmin[1][r] = fminf(rmin[1][r], d); cm1 = fminf(cm1, d);
    }
    cm0 = fminf(cm0, __shfl_xor(cm0, 32));
    cm1 = fminf(cm1, __shfl_xor(cm1, 32));
    if (lane < 32) {
      atomicMin(&colmin_lds[j0t + la31],      __float_as_uint(cm0));
      atomicMin(&colmin_lds[j0t + 32 + la31], __float_as_uint(cm1));
    }
    // land the prefetched tile into the other buffer (linear, conflict-free)
    if (jt < 15) {
      char* dst = (char*)ys[cur ^ 1];
      *(uint4*)(dst + (size_t)(tid)        * 16) = stg0;
      *(uint4*)(dst + (size_t)(512  + tid) * 16) = stg1;
      *(uint4*)(dst + (size_t)(1024 + tid) * 16) = stg2;
      *(uint4*)(dst + (size_t)(1536 + tid) * 16) = stg3;
    }
    __syncthreads();
  }

  // colmin: all LDS atomics complete as of the loop's final barrier
  for (int idx = tid; idx < NPTS; idx += 512)
    atomicMin(&colming[idx], colmin_lds[idx]);

  // rowmin: reduce across the 32 j-lanes, write direct (rows owned by block)
#pragma unroll
  for (int fm = 0; fm < 2; ++fm)
#pragma unroll
    for (int r = 0; r < 16; ++r) {
      float v = rmin[fm][r];
      v = fminf(v, __shfl_xor(v, 1));
      v = fminf(v, __shfl_xor(v, 2));
      v = fminf(v, __shfl_xor(v, 4));
      v = fminf(v, __shfl_xor(v, 8));
      v = fminf(v, __shfl_xor(v, 16));
      if (la31 == 0) {
        int row = qrow * 64 + fm * 32 + (r & 3) + ((r >> 2) << 3) + (la5 << 2);
        rowming[i0 + row] = v;
      }
    }
}

// ---------------- kernel 3: masked sums + mean ----------------
__global__ void chamfer_reduce(const char* __restrict__ ws, const void* __restrict__ mask,
                               float* __restrict__ out) {
  __shared__ float red[256];
  int b = blockIdx.x;
  int tid = threadIdx.x;
  bool i32 = mask_is_i32(mask);
  const float*    rowmin = (const float*)(ws + OFF_RMIN) + b * NPTS;
  const unsigned* colmin = (const unsigned*)(ws + OFF_CMIN) + b * NPTS;
  float s = 0.f;
  for (int i = tid; i < NPTS; i += 256) {
    if (mask_at(mask, i32, b * NPTS + i))
      s += rowmin[i] + __uint_as_float(colmin[i]);
  }
  red[tid] = s;
  __syncthreads();
  for (int st = 128; st > 0; st >>= 1) {
    if (tid < st) red[tid] += red[tid + st];
    __syncthreads();
  }
  if (tid == 0) atomicAdd(out, red[0] * (1.f / BATCH));
}

extern "C" void kernel_launch(void* const* d_in, const int* in_sizes, int n_in,
                              void* d_out, int out_size, void* d_ws, size_t ws_size,
                              hipStream_t stream) {
  const float* x = (const float*)d_in[0];
  const float* y = (const float*)d_in[1];
  const void* mask = d_in[2];
  float* out = (float*)d_out;
  char* ws = (char*)d_ws;

  chamfer_prep<<<1024, 256, 0, stream>>>(x, y, mask, ws, out);
  chamfer_dist<<<256, 512, 0, stream>>>(ws);
  chamfer_reduce<<<32, 256, 0, stream>>>(ws, mask, out);
}